// Round 1
// baseline (328.215 us; speedup 1.0000x reference)
//
#include <hip/hip_runtime.h>
#include <stdint.h>
#include <math.h>

#define BB 64
#define SS 2048
#define DD 128
#define NB 48
#define NTOK 100000
#define HALF 8388608u   // (BB*SS*DD)/2 = 2^23
#define KL_OFF (BB*NB*DD) // 393216

__device__ __forceinline__ uint32_t rotl32(uint32_t x, uint32_t r){ return (x<<r)|(x>>(32u-r)); }

// JAX threefry2x32 with key = (0, 42)  [jax.random.key(42)]
__device__ __forceinline__ uint2 threefry_0_42(uint32_t x0, uint32_t x1){
  const uint32_t ks0 = 0u, ks1 = 42u, ks2 = 0x1BD11BDAu ^ 0u ^ 42u; // 0x1BD11BF0
  x0 += ks0; x1 += ks1;
#define TF_ROUND(r) { x0 += x1; x1 = rotl32(x1, r); x1 ^= x0; }
  TF_ROUND(13u) TF_ROUND(15u) TF_ROUND(26u) TF_ROUND(6u)
  x0 += ks1; x1 += ks2 + 1u;
  TF_ROUND(17u) TF_ROUND(29u) TF_ROUND(16u) TF_ROUND(24u)
  x0 += ks2; x1 += ks0 + 2u;
  TF_ROUND(13u) TF_ROUND(15u) TF_ROUND(26u) TF_ROUND(6u)
  x0 += ks0; x1 += ks1 + 3u;
  TF_ROUND(17u) TF_ROUND(29u) TF_ROUND(16u) TF_ROUND(24u)
  x0 += ks1; x1 += ks2 + 4u;
  TF_ROUND(13u) TF_ROUND(15u) TF_ROUND(26u) TF_ROUND(6u)
  x0 += ks2; x1 += ks0 + 5u;
#undef TF_ROUND
  return make_uint2(x0, x1);
}

// XLA f32 ErfInv (Giles polynomial) — matches lax.erf_inv lowering
__device__ __forceinline__ float xla_erfinv(float x){
  float w = -log1pf(-(x*x));
  float p;
  if (w < 5.0f){
    w = w - 2.5f;
    p = 2.81022636e-08f;
    p = 3.43273939e-07f + p*w;
    p = -3.5233877e-06f + p*w;
    p = -4.39150654e-06f + p*w;
    p = 0.00021858087f  + p*w;
    p = -0.00125372503f + p*w;
    p = -0.00417768164f + p*w;
    p = 0.246640727f    + p*w;
    p = 1.50140941f     + p*w;
  } else {
    w = sqrtf(w) - 3.0f;
    p = -0.000200214257f;
    p = 0.000100950558f + p*w;
    p = 0.00134934322f  + p*w;
    p = -0.00367342844f + p*w;
    p = 0.00573950773f  + p*w;
    p = -0.0076224613f  + p*w;
    p = 0.00943887047f  + p*w;
    p = 1.00167406f     + p*w;
    p = 2.83297682f     + p*w;
  }
  return p * x;
}

// JAX normal from raw 32 bits: uniform in [-0.99999994, 1) then sqrt(2)*erfinv
__device__ __forceinline__ float jax_normal_from_bits(uint32_t bits){
  float f   = __uint_as_float((bits >> 9) | 0x3F800000u);
  float u01 = f - 1.0f;                         // [0,1), exact
  const float lo = __uint_as_float(0xBF7FFFFFu); // nextafter(-1,0)
  float r = u01 * 2.0f + lo;                    // scale fl(1-lo)=2.0 exactly; 2*u01 exact
  float u = fmaxf(lo, r);
  return (float)M_SQRT2 * xla_erfinv(u);
}

// K0: per-token logvar row sum, replicating 8-accumulator (stride-8) x seq16 + pairwise tree
__global__ __launch_bounds__(256) void k_lsum(const float* __restrict__ W, float* __restrict__ lsum){
  __shared__ float st[256];
  __shared__ float part[16];
  int t = threadIdx.x;
  int sub = t >> 7, dim = t & 127;
  int tok = blockIdx.x*2 + sub;
  float v = 0.f;
  if (tok < NTOK) v = W[tok*256 + 128 + dim];
  st[t] = v;
  __syncthreads();
  if (dim < 8){
    int base = sub*128;
    float a = st[base + dim];
    #pragma unroll
    for (int k=1;k<16;k++) a = __fadd_rn(a, st[base + 8*k + dim]);
    part[sub*8 + dim] = a;
  }
  __syncthreads();
  if (dim == 0 && tok < NTOK){
    const float* p = &part[sub*8];
    float s01 = __fadd_rn(p[0],p[1]);
    float s23 = __fadd_rn(p[2],p[3]);
    float s45 = __fadd_rn(p[4],p[5]);
    float s67 = __fadd_rn(p[6],p[7]);
    lsum[tok] = __fadd_rn(__fadd_rn(s01,s23), __fadd_rn(s45,s67));
  }
}

// K1: H -> Brent-Kung scan (exact JAX associative_scan recursion) -> normalize -> bins
__global__ __launch_bounds__(256) void k_bins(const float* __restrict__ X, const float* __restrict__ lsum,
                                              int8_t* __restrict__ bins){
  __shared__ float buf[4096];   // level L at offset 4096 - (4096>>L), size 2048>>L
  __shared__ float red[256];
  int b = blockIdx.x, t = threadIdx.x;
  // L = correctly-rounded f32 log of f32(2*pi); C1 = fl(128 + fl(128*L))
  float twopi_f = (float)(2.0 * M_PI);
  float L = (float)log((double)twopi_f);
  float C1 = __fadd_rn(128.0f, __fmul_rn(128.0f, L));
  for (int s=t; s<SS; s+=256){
    float T    = X[(b*SS+s)*2 + 0];
    int   tok  = (int)X[(b*SS+s)*2 + 1];
    float ls   = lsum[tok];
    float h    = __fmul_rn(0.5f, __fadd_rn(C1, ls));
    float mask = (T < 48.0f) ? 1.0f : 0.0f;
    buf[s] = __fmul_rn(h, mask);
  }
  __syncthreads();
  // up-sweep: reduced[k] = a[2k] + a[2k+1]
  {
    int offL = 0, sz = SS;
    for (int lev=0; lev<11; lev++){
      int n = sz >> 1; int offN = offL + sz;
      for (int k=t; k<n; k+=256)
        buf[offN + k] = __fadd_rn(buf[offL + 2*k], buf[offL + 2*k + 1]);
      __syncthreads();
      offL = offN; sz = n;
    }
  }
  // down-sweep: S_L[2k+1] = S_{L+1}[k]; S_L[0]=a[0]; S_L[2k] = S_{L+1}[k-1] + a[2k]
  for (int lev=10; lev>=0; lev--){
    int offC = 4096 - (4096 >> lev);
    int offN = 4096 - (4096 >> (lev+1));
    int half = (2048 >> lev) >> 1;
    for (int k=t; k<half; k+=256){
      float odd  = buf[offN + k];
      float even = (k == 0) ? buf[offC] : __fadd_rn(buf[offN + k - 1], buf[offC + 2*k]);
      buf[offC + 2*k]     = even;
      buf[offC + 2*k + 1] = odd;
    }
    __syncthreads();
  }
  // max over row (exact)
  float m = -INFINITY;
  for (int s=t; s<SS; s+=256) m = fmaxf(m, buf[s]);
  red[t] = m; __syncthreads();
  for (int w=128; w>0; w>>=1){ if (t<w) red[t] = fmaxf(red[t], red[t+w]); __syncthreads(); }
  float maxv = red[0];
  for (int s=t; s<SS; s+=256){
    float norm = __fdiv_rn(buf[s], maxv);
    int bin = (int)floorf(__fmul_rn(norm, 48.0f));
    bool valid = (norm >= 0.0f) && (norm < 1.0f);
    bins[b*SS + s] = valid ? (int8_t)bin : (int8_t)(-1);
  }
}

// K2: gather W rows, reconstruct eps, accumulate into per-(row,chunk) LDS bins, + kl
__global__ __launch_bounds__(256) void k_accum(const float* __restrict__ X, const float* __restrict__ W,
                                               const int8_t* __restrict__ bins, float* __restrict__ out){
  __shared__ float acc[NB*DD];
  __shared__ double klred[256];
  __shared__ int minb_s, maxb_s;
  int t = threadIdx.x;
  int b = blockIdx.x >> 3;
  int chunk = blockIdx.x & 7;
  for (int i=t; i<NB*DD; i+=256) acc[i] = 0.f;
  if (t==0){ minb_s = 1000; maxb_s = -1; }
  __syncthreads();
  int sub = t >> 7, lane = t & 127;
  double kl = 0.0;
  int mymin = 1000, mymax = -1;
  for (int it=0; it<128; it++){
    int s   = chunk*256 + it*2 + sub;
    int idx = b*SS + s;
    int tok = (int)X[idx*2 + 1];
    float mu = W[tok*256 + lane];
    float lv = W[tok*256 + 128 + lane];
    kl += (double)((-1.0f - lv) + mu*mu + expf(lv));
    uint32_t i32 = (uint32_t)idx * 128u + (uint32_t)lane;
    float z;
    if (i32 < HALF){ uint2 r = threefry_0_42(i32, i32 + HALF); z = jax_normal_from_bits(r.x); }
    else           { uint2 r = threefry_0_42(i32 - HALF, i32); z = jax_normal_from_bits(r.y); }
    float emb = mu + expf(0.5f*lv)*z;
    int bin = (int)bins[idx];
    if (bin >= 0){
      atomicAdd(&acc[bin*DD + lane], emb);
      mymin = min(mymin, bin); mymax = max(mymax, bin);
    }
  }
  atomicMin(&minb_s, mymin); atomicMax(&maxb_s, mymax);
  klred[t] = kl;
  __syncthreads();
  for (int w=128; w>0; w>>=1){ if (t<w) klred[t] += klred[t+w]; __syncthreads(); }
  if (t==0) atomicAdd(&out[KL_OFF], (float)(klred[0] * (0.5/64.0)));
  int lo = minb_s, hi = maxb_s;
  if (hi >= lo){
    int total = (hi - lo + 1)*DD;
    for (int q=t; q<total; q+=256){
      int bin = lo + q/DD; int dim = q - (q/DD)*DD;
      float v = acc[bin*DD + dim];
      if (v != 0.0f) atomicAdd(&out[(b*NB + bin)*DD + dim], v);
    }
  }
}

extern "C" void kernel_launch(void* const* d_in, const int* in_sizes, int n_in,
                              void* d_out, int out_size, void* d_ws, size_t ws_size,
                              hipStream_t stream){
  const float* X = (const float*)d_in[0];
  const float* W = (const float*)d_in[1];
  float* out = (float*)d_out;
  float* lsum = (float*)d_ws;                                  // 100000 floats
  int8_t* bins = (int8_t*)((char*)d_ws + NTOK*sizeof(float));  // 131072 bytes
  (void)in_sizes; (void)n_in; (void)ws_size;
  hipMemsetAsync(d_out, 0, (size_t)out_size*sizeof(float), stream);
  k_lsum <<<(NTOK+1)/2, 256, 0, stream>>>(W, lsum);
  k_bins <<<BB,          256, 0, stream>>>(X, lsum, bins);
  k_accum<<<BB*8,        256, 0, stream>>>(X, W, bins, out);
}

// Round 2
// 276.545 us; speedup vs baseline: 1.1868x; 1.1868x over previous
//
#include <hip/hip_runtime.h>
#include <stdint.h>
#include <math.h>

#define BB 64
#define SS 2048
#define DD 128
#define NB 48
#define NTOK 100000
#define HALF 8388608u   // (BB*SS*DD)/2 = 2^23
#define KL_OFF (BB*NB*DD) // 393216
#define WIN 16

__device__ __forceinline__ uint32_t rotl32(uint32_t x, uint32_t r){ return (x<<r)|(x>>(32u-r)); }

// JAX threefry2x32 with key = (0, 42)  [jax.random.key(42)]
__device__ __forceinline__ uint2 threefry_0_42(uint32_t x0, uint32_t x1){
  const uint32_t ks0 = 0u, ks1 = 42u, ks2 = 0x1BD11BDAu ^ 0u ^ 42u; // 0x1BD11BF0
  x0 += ks0; x1 += ks1;
#define TF_ROUND(r) { x0 += x1; x1 = rotl32(x1, r); x1 ^= x0; }
  TF_ROUND(13u) TF_ROUND(15u) TF_ROUND(26u) TF_ROUND(6u)
  x0 += ks1; x1 += ks2 + 1u;
  TF_ROUND(17u) TF_ROUND(29u) TF_ROUND(16u) TF_ROUND(24u)
  x0 += ks2; x1 += ks0 + 2u;
  TF_ROUND(13u) TF_ROUND(15u) TF_ROUND(26u) TF_ROUND(6u)
  x0 += ks0; x1 += ks1 + 3u;
  TF_ROUND(17u) TF_ROUND(29u) TF_ROUND(16u) TF_ROUND(24u)
  x0 += ks1; x1 += ks2 + 4u;
  TF_ROUND(13u) TF_ROUND(15u) TF_ROUND(26u) TF_ROUND(6u)
  x0 += ks2; x1 += ks0 + 5u;
#undef TF_ROUND
  return make_uint2(x0, x1);
}

// XLA f32 ErfInv (Giles polynomial) — matches lax.erf_inv lowering
__device__ __forceinline__ float xla_erfinv(float x){
  float w = -log1pf(-(x*x));
  float p;
  if (w < 5.0f){
    w = w - 2.5f;
    p = 2.81022636e-08f;
    p = 3.43273939e-07f + p*w;
    p = -3.5233877e-06f + p*w;
    p = -4.39150654e-06f + p*w;
    p = 0.00021858087f  + p*w;
    p = -0.00125372503f + p*w;
    p = -0.00417768164f + p*w;
    p = 0.246640727f    + p*w;
    p = 1.50140941f     + p*w;
  } else {
    w = sqrtf(w) - 3.0f;
    p = -0.000200214257f;
    p = 0.000100950558f + p*w;
    p = 0.00134934322f  + p*w;
    p = -0.00367342844f + p*w;
    p = 0.00573950773f  + p*w;
    p = -0.0076224613f  + p*w;
    p = 0.00943887047f  + p*w;
    p = 1.00167406f     + p*w;
    p = 2.83297682f     + p*w;
  }
  return p * x;
}

// JAX normal from raw 32 bits: uniform in [-0.99999994, 1) then sqrt(2)*erfinv
__device__ __forceinline__ float jax_normal_from_bits(uint32_t bits){
  float f   = __uint_as_float((bits >> 9) | 0x3F800000u);
  float u01 = f - 1.0f;                         // [0,1), exact
  const float lo = __uint_as_float(0xBF7FFFFFu); // nextafter(-1,0)
  float r = u01 * 2.0f + lo;                    // scale fl(1-lo)=2.0 exactly; 2*u01 exact
  float u = fmaxf(lo, r);
  return (float)M_SQRT2 * xla_erfinv(u);
}

// K0: 8 tokens/block, coalesced. lsum[tok] (bit-exact association: 8 accumulators
// stride-8 x seq16, then pairwise tree) + g[tok] = sum_d(-1-lv+mu^2+exp(lv)).
__global__ __launch_bounds__(256) void k_prep(const float* __restrict__ W,
                                              float* __restrict__ lsum,
                                              float* __restrict__ g){
  __shared__ float mu_s[8][128];
  __shared__ float lv_s[8][128];
  __shared__ float gpart[8][32];
  __shared__ float apart[8][8];
  int t = threadIdx.x;
  int blk = blockIdx.x;
  #pragma unroll
  for (int r=0;r<8;r++){
    float v = W[(size_t)blk*2048 + r*256 + t];
    if (t < 128) mu_s[r][t] = v; else lv_s[r][t-128] = v;
  }
  __syncthreads();
  {
    int tl = t>>5, i = t&31;
    float gp = 0.f;
    #pragma unroll
    for (int c=0;c<4;c++){
      int d = i + 32*c;
      float mu = mu_s[tl][d], lv = lv_s[tl][d];
      gp += (-1.0f - lv) + mu*mu + expf(lv);
    }
    gpart[tl][i] = gp;
  }
  if (t < 64){
    int tl = t>>3, j = t&7;
    float a = lv_s[tl][j];
    #pragma unroll
    for (int k=1;k<16;k++) a = __fadd_rn(a, lv_s[tl][8*k+j]);
    apart[tl][j] = a;
  }
  __syncthreads();
  if (t < 8){
    const float* p = apart[t];
    float s01 = __fadd_rn(p[0],p[1]);
    float s23 = __fadd_rn(p[2],p[3]);
    float s45 = __fadd_rn(p[4],p[5]);
    float s67 = __fadd_rn(p[6],p[7]);
    lsum[blk*8 + t] = __fadd_rn(__fadd_rn(s01,s23), __fadd_rn(s45,s67));
    float gs = 0.f;
    #pragma unroll
    for (int i=0;i<32;i++) gs += gpart[t][i];
    g[blk*8 + t] = gs;
  }
}

// K1: H -> Brent-Kung scan (exact JAX associative_scan recursion) -> normalize -> bins
// UNCHANGED from round 1 — bit-exact verified, do not touch.
__global__ __launch_bounds__(256) void k_bins(const float* __restrict__ X, const float* __restrict__ lsum,
                                              int8_t* __restrict__ bins){
  __shared__ float buf[4096];   // level L at offset 4096 - (4096>>L), size 2048>>L
  __shared__ float red[256];
  int b = blockIdx.x, t = threadIdx.x;
  float twopi_f = (float)(2.0 * M_PI);
  float L = (float)log((double)twopi_f);
  float C1 = __fadd_rn(128.0f, __fmul_rn(128.0f, L));
  for (int s=t; s<SS; s+=256){
    float T    = X[(b*SS+s)*2 + 0];
    int   tok  = (int)X[(b*SS+s)*2 + 1];
    float ls   = lsum[tok];
    float h    = __fmul_rn(0.5f, __fadd_rn(C1, ls));
    float mask = (T < 48.0f) ? 1.0f : 0.0f;
    buf[s] = __fmul_rn(h, mask);
  }
  __syncthreads();
  {
    int offL = 0, sz = SS;
    for (int lev=0; lev<11; lev++){
      int n = sz >> 1; int offN = offL + sz;
      for (int k=t; k<n; k+=256)
        buf[offN + k] = __fadd_rn(buf[offL + 2*k], buf[offL + 2*k + 1]);
      __syncthreads();
      offL = offN; sz = n;
    }
  }
  for (int lev=10; lev>=0; lev--){
    int offC = 4096 - (4096 >> lev);
    int offN = 4096 - (4096 >> (lev+1));
    int half = (2048 >> lev) >> 1;
    for (int k=t; k<half; k+=256){
      float odd  = buf[offN + k];
      float even = (k == 0) ? buf[offC] : __fadd_rn(buf[offN + k - 1], buf[offC + 2*k]);
      buf[offC + 2*k]     = even;
      buf[offC + 2*k + 1] = odd;
    }
    __syncthreads();
  }
  float m = -INFINITY;
  for (int s=t; s<SS; s+=256) m = fmaxf(m, buf[s]);
  red[t] = m; __syncthreads();
  for (int w=128; w>0; w>>=1){ if (t<w) red[t] = fmaxf(red[t], red[t+w]); __syncthreads(); }
  float maxv = red[0];
  for (int s=t; s<SS; s+=256){
    float norm = __fdiv_rn(buf[s], maxv);
    int bin = (int)floorf(__fmul_rn(norm, 48.0f));
    bool valid = (norm >= 0.0f) && (norm < 1.0f);
    bins[b*SS + s] = valid ? (int8_t)bin : (int8_t)(-1);
  }
}

// K2: row-pair (b, b+32) shares one threefry call per (s,d). 16-bin LDS window
// (bins nondecreasing per row; out-of-window -> direct global atomic). kl from g[].
__global__ __launch_bounds__(256, 8) void k_accum(const float* __restrict__ X, const float* __restrict__ W,
                                                  const int8_t* __restrict__ bins,
                                                  const float* __restrict__ g,
                                                  float* __restrict__ out){
  __shared__ float acc[2*WIN*DD];   // 16 KB
  __shared__ int maxb[2];
  __shared__ double klred[2];
  int t = threadIdx.x;
  int bp = blockIdx.x >> 6;          // 0..31 -> rows (bp, bp+32)
  int chunk = blockIdx.x & 63;       // 32 positions each
  int sub = t >> 7, lane = t & 127;
  for (int i=t; i<2*WIN*DD; i+=256) acc[i] = 0.f;
  if (t < 2) maxb[t] = -1;
  int w0 = bins[bp*SS + chunk*32];        // window bases (broadcast loads)
  int w1 = bins[(bp+32)*SS + chunk*32];
  __syncthreads();
  int mymax0 = -1, mymax1 = -1;
  double kl = 0.0;
  for (int it=0; it<16; it++){
    int s = chunk*32 + it*2 + sub;
    int idx0 = bp*SS + s;
    int idx1 = idx0 + 32*SS;
    int tok0 = (int)X[idx0*2 + 1];
    int tok1 = (int)X[idx1*2 + 1];
    float mu0 = W[tok0*256 + lane], lv0 = W[tok0*256 + 128 + lane];
    float mu1 = W[tok1*256 + lane], lv1 = W[tok1*256 + 128 + lane];
    uint32_t i32 = (uint32_t)idx0 * 128u + (uint32_t)lane;   // < 2^23
    uint2 r = threefry_0_42(i32, i32 + HALF);
    float e0 = mu0 + expf(0.5f*lv0) * jax_normal_from_bits(r.x);
    float e1 = mu1 + expf(0.5f*lv1) * jax_normal_from_bits(r.y);
    int b0 = (int)bins[idx0];
    int b1 = (int)bins[idx1];
    if (b0 >= 0){
      int o = b0 - w0;
      if (o < WIN){ atomicAdd(&acc[o*DD + lane], e0); mymax0 = max(mymax0, b0); }
      else atomicAdd(&out[(bp*NB + b0)*DD + lane], e0);
    }
    if (b1 >= 0){
      int o = b1 - w1;
      if (o < WIN){ atomicAdd(&acc[WIN*DD + o*DD + lane], e1); mymax1 = max(mymax1, b1); }
      else atomicAdd(&out[((bp+32)*NB + b1)*DD + lane], e1);
    }
    if (lane == 0) kl += (double)g[tok0] + (double)g[tok1];
  }
  atomicMax(&maxb[0], mymax0);
  atomicMax(&maxb[1], mymax1);
  if (lane == 0) klred[sub] = kl;
  __syncthreads();
  if (t == 0) atomicAdd(&out[KL_OFF], (float)((klred[0] + klred[1]) * (0.5/64.0)));
  // emit window rows
  int h0 = maxb[0], h1 = maxb[1];
  if (h0 >= w0 && h0 >= 0){
    int total = (h0 - w0 + 1)*DD;
    for (int q=t; q<total; q+=256){
      int o = q/DD, dim = q - o*DD;
      atomicAdd(&out[(bp*NB + w0 + o)*DD + dim], acc[o*DD + dim]);
    }
  }
  if (h1 >= w1 && h1 >= 0){
    int total = (h1 - w1 + 1)*DD;
    for (int q=t; q<total; q+=256){
      int o = q/DD, dim = q - o*DD;
      atomicAdd(&out[((bp+32)*NB + w1 + o)*DD + dim], acc[WIN*DD + o*DD + dim]);
    }
  }
}

extern "C" void kernel_launch(void* const* d_in, const int* in_sizes, int n_in,
                              void* d_out, int out_size, void* d_ws, size_t ws_size,
                              hipStream_t stream){
  const float* X = (const float*)d_in[0];
  const float* W = (const float*)d_in[1];
  float* out  = (float*)d_out;
  float* lsum = (float*)d_ws;                                        // 100000 f
  float* g    = (float*)((char*)d_ws + 400000);                      // 100000 f
  int8_t* bins = (int8_t*)((char*)d_ws + 800000);                    // 131072 B
  (void)in_sizes; (void)n_in; (void)ws_size;
  hipMemsetAsync(d_out, 0, (size_t)out_size*sizeof(float), stream);
  k_prep <<<NTOK/8, 256, 0, stream>>>(W, lsum, g);
  k_bins <<<BB,     256, 0, stream>>>(X, lsum, bins);
  k_accum<<<2048,   256, 0, stream>>>(X, W, bins, g, out);
}

// Round 3
// 261.223 us; speedup vs baseline: 1.2565x; 1.0587x over previous
//
#include <hip/hip_runtime.h>
#include <stdint.h>
#include <math.h>

#define BB 64
#define SS 2048
#define DD 128
#define NB 48
#define NTOK 100000
#define HALF 8388608u   // (BB*SS*DD)/2 = 2^23
#define KL_OFF (BB*NB*DD) // 393216
#define WIN 16

__device__ __forceinline__ uint32_t rotl32(uint32_t x, uint32_t r){ return (x<<r)|(x>>(32u-r)); }

// JAX threefry2x32 with key = (0, 42) — bit-exact, do not touch.
__device__ __forceinline__ uint2 threefry_0_42(uint32_t x0, uint32_t x1){
  const uint32_t ks0 = 0u, ks1 = 42u, ks2 = 0x1BD11BDAu ^ 0u ^ 42u; // 0x1BD11BF0
  x0 += ks0; x1 += ks1;
#define TF_ROUND(r) { x0 += x1; x1 = rotl32(x1, r); x1 ^= x0; }
  TF_ROUND(13u) TF_ROUND(15u) TF_ROUND(26u) TF_ROUND(6u)
  x0 += ks1; x1 += ks2 + 1u;
  TF_ROUND(17u) TF_ROUND(29u) TF_ROUND(16u) TF_ROUND(24u)
  x0 += ks2; x1 += ks0 + 2u;
  TF_ROUND(13u) TF_ROUND(15u) TF_ROUND(26u) TF_ROUND(6u)
  x0 += ks0; x1 += ks1 + 3u;
  TF_ROUND(17u) TF_ROUND(29u) TF_ROUND(16u) TF_ROUND(24u)
  x0 += ks1; x1 += ks2 + 4u;
  TF_ROUND(13u) TF_ROUND(15u) TF_ROUND(26u) TF_ROUND(6u)
  x0 += ks2; x1 += ks0 + 5u;
#undef TF_ROUND
  return make_uint2(x0, x1);
}

// Branchless fast erfinv (Giles coeffs, HW log/sqrt). Feeds ONLY the
// tolerance-checked emb output — bins never see z. fma(x,-x,1) keeps the
// 1-x^2 cancellation single-rounded so the tail stays accurate.
__device__ __forceinline__ float fast_erfinv(float x){
  float w = -__logf(__fmaf_rn(x, -x, 1.0f));
  bool c = w < 5.0f;
  float t = c ? (w - 2.5f) : (__builtin_amdgcn_sqrtf(w) - 3.0f);
  float p =              c ? 2.81022636e-08f : -0.000200214257f;
  p = __fmaf_rn(p, t,    c ? 3.43273939e-07f : 0.000100950558f);
  p = __fmaf_rn(p, t,    c ? -3.5233877e-06f : 0.00134934322f);
  p = __fmaf_rn(p, t,    c ? -4.39150654e-06f : -0.00367342844f);
  p = __fmaf_rn(p, t,    c ? 0.00021858087f  : 0.00573950773f);
  p = __fmaf_rn(p, t,    c ? -0.00125372503f : -0.0076224613f);
  p = __fmaf_rn(p, t,    c ? -0.00417768164f : 0.00943887047f);
  p = __fmaf_rn(p, t,    c ? 0.246640727f    : 1.00167406f);
  p = __fmaf_rn(p, t,    c ? 1.50140941f     : 2.83297682f);
  return p * x;
}

__device__ __forceinline__ float jax_normal_from_bits(uint32_t bits){
  float f   = __uint_as_float((bits >> 9) | 0x3F800000u);
  float u01 = f - 1.0f;                          // [0,1), exact
  const float lo = __uint_as_float(0xBF7FFFFFu); // nextafter(-1,0)
  float u = fmaxf(lo, __fmaf_rn(u01, 2.0f, lo));
  return 1.41421356237f * fast_erfinv(u);
}

// K0: 8 tokens/block, float4 loads. lsum[tok] keeps the BIT-EXACT association
// (8 accumulators stride-8 x seq16, then pairwise tree) — do not touch.
// g[tok] = sum_d(-1-lv+mu^2+exp(lv)) is tolerance-checked -> __expf ok.
__global__ __launch_bounds__(256) void k_prep(const float4* __restrict__ W4,
                                              float* __restrict__ lsum,
                                              float* __restrict__ g){
  __shared__ float mu_s[8][128];
  __shared__ float lv_s[8][128];
  __shared__ float gpart[8][32];
  __shared__ float apart[8][8];
  int t = threadIdx.x;
  int blk = blockIdx.x;
  #pragma unroll
  for (int h=0; h<2; h++){
    int q = h*256 + t;          // 0..511 = 8 tokens x 64 float4
    int r = q >> 6, c = q & 63;
    float4 v = W4[(size_t)blk*512 + q];
    if (c < 32) ((float4*)mu_s[r])[c]      = v;
    else        ((float4*)lv_s[r])[c - 32] = v;
  }
  __syncthreads();
  {
    int tl = t>>5, i = t&31;
    float gp = 0.f;
    #pragma unroll
    for (int c=0;c<4;c++){
      int d = i + 32*c;
      float mu = mu_s[tl][d], lv = lv_s[tl][d];
      gp += (-1.0f - lv) + mu*mu + __expf(lv);
    }
    gpart[tl][i] = gp;
  }
  if (t < 64){
    int tl = t>>3, j = t&7;
    float a = lv_s[tl][j];
    #pragma unroll
    for (int k=1;k<16;k++) a = __fadd_rn(a, lv_s[tl][8*k+j]);
    apart[tl][j] = a;
  }
  __syncthreads();
  if (t < 8){
    const float* p = apart[t];
    float s01 = __fadd_rn(p[0],p[1]);
    float s23 = __fadd_rn(p[2],p[3]);
    float s45 = __fadd_rn(p[4],p[5]);
    float s67 = __fadd_rn(p[6],p[7]);
    lsum[blk*8 + t] = __fadd_rn(__fadd_rn(s01,s23), __fadd_rn(s45,s67));
    float gs = 0.f;
    #pragma unroll
    for (int i=0;i<32;i++) gs += gpart[t][i];
    g[blk*8 + t] = gs;
  }
}

// K1: H -> Brent-Kung scan (exact JAX associative_scan recursion) -> normalize
// -> bins. Scan/normalize/floor path is BIT-EXACT verified — do not touch.
// Added: kl accumulation from g[] (tolerance-checked, f32).
__global__ __launch_bounds__(256) void k_bins(const float* __restrict__ X, const float* __restrict__ lsum,
                                              const float* __restrict__ g,
                                              int8_t* __restrict__ bins, float* __restrict__ out){
  __shared__ float buf[4096];   // level L at offset 4096 - (4096>>L), size 2048>>L
  __shared__ float red[256];
  int b = blockIdx.x, t = threadIdx.x;
  float twopi_f = (float)(2.0 * M_PI);
  float L = (float)log((double)twopi_f);
  float C1 = __fadd_rn(128.0f, __fmul_rn(128.0f, L));
  float klacc = 0.f;
  for (int s=t; s<SS; s+=256){
    float T    = X[(b*SS+s)*2 + 0];
    int   tok  = (int)X[(b*SS+s)*2 + 1];
    float ls   = lsum[tok];
    klacc     += g[tok];
    float h    = __fmul_rn(0.5f, __fadd_rn(C1, ls));
    float mask = (T < 48.0f) ? 1.0f : 0.0f;
    buf[s] = __fmul_rn(h, mask);
  }
  __syncthreads();
  {
    int offL = 0, sz = SS;
    for (int lev=0; lev<11; lev++){
      int n = sz >> 1; int offN = offL + sz;
      for (int k=t; k<n; k+=256)
        buf[offN + k] = __fadd_rn(buf[offL + 2*k], buf[offL + 2*k + 1]);
      __syncthreads();
      offL = offN; sz = n;
    }
  }
  for (int lev=10; lev>=0; lev--){
    int offC = 4096 - (4096 >> lev);
    int offN = 4096 - (4096 >> (lev+1));
    int half = (2048 >> lev) >> 1;
    for (int k=t; k<half; k+=256){
      float odd  = buf[offN + k];
      float even = (k == 0) ? buf[offC] : __fadd_rn(buf[offN + k - 1], buf[offC + 2*k]);
      buf[offC + 2*k]     = even;
      buf[offC + 2*k + 1] = odd;
    }
    __syncthreads();
  }
  float m = -INFINITY;
  for (int s=t; s<SS; s+=256) m = fmaxf(m, buf[s]);
  red[t] = m; __syncthreads();
  for (int w=128; w>0; w>>=1){ if (t<w) red[t] = fmaxf(red[t], red[t+w]); __syncthreads(); }
  float maxv = red[0];
  for (int s=t; s<SS; s+=256){
    float norm = __fdiv_rn(buf[s], maxv);
    int bin = (int)floorf(__fmul_rn(norm, 48.0f));
    bool valid = (norm >= 0.0f) && (norm < 1.0f);
    bins[b*SS + s] = valid ? (int8_t)bin : (int8_t)(-1);
  }
  __syncthreads();
  red[t] = klacc; __syncthreads();
  for (int w=128; w>0; w>>=1){ if (t<w) red[t] += red[t+w]; __syncthreads(); }
  if (t==0) atomicAdd(&out[KL_OFF], red[0] * (0.5f/64.0f));
}

// K2: row-pair (b, b+32) shares one threefry per (s,d). 16-bin LDS window
// (bins nondecreasing per row; out-of-window -> direct global atomic).
__global__ __launch_bounds__(256, 8) void k_accum(const float* __restrict__ X, const float* __restrict__ W,
                                                  const int8_t* __restrict__ bins,
                                                  float* __restrict__ out){
  __shared__ float acc[2*WIN*DD];   // 16 KB
  __shared__ int maxb[2];
  int t = threadIdx.x;
  int bp = blockIdx.x >> 6;          // 0..31 -> rows (bp, bp+32)
  int chunk = blockIdx.x & 63;       // 32 positions each
  int sub = t >> 7, lane = t & 127;
  for (int i=t; i<2*WIN*DD; i+=256) acc[i] = 0.f;
  if (t < 2) maxb[t] = -1;
  int w0 = bins[bp*SS + chunk*32];        // window bases (broadcast loads)
  int w1 = bins[(bp+32)*SS + chunk*32];
  __syncthreads();
  int mymax0 = -1, mymax1 = -1;
  for (int it=0; it<16; it++){
    int s = chunk*32 + it*2 + sub;
    int idx0 = bp*SS + s;
    int idx1 = idx0 + 32*SS;
    int tok0 = (int)X[idx0*2 + 1];
    int tok1 = (int)X[idx1*2 + 1];
    float mu0 = W[tok0*256 + lane], lv0 = W[tok0*256 + 128 + lane];
    float mu1 = W[tok1*256 + lane], lv1 = W[tok1*256 + 128 + lane];
    uint32_t i32 = (uint32_t)idx0 * 128u + (uint32_t)lane;   // < 2^23
    uint2 r = threefry_0_42(i32, i32 + HALF);
    float e0 = __fmaf_rn(__expf(0.5f*lv0), jax_normal_from_bits(r.x), mu0);
    float e1 = __fmaf_rn(__expf(0.5f*lv1), jax_normal_from_bits(r.y), mu1);
    int b0 = (int)bins[idx0];
    int b1 = (int)bins[idx1];
    if (b0 >= 0){
      int o = b0 - w0;
      if (o < WIN){ atomicAdd(&acc[o*DD + lane], e0); mymax0 = max(mymax0, b0); }
      else atomicAdd(&out[(bp*NB + b0)*DD + lane], e0);
    }
    if (b1 >= 0){
      int o = b1 - w1;
      if (o < WIN){ atomicAdd(&acc[WIN*DD + o*DD + lane], e1); mymax1 = max(mymax1, b1); }
      else atomicAdd(&out[((bp+32)*NB + b1)*DD + lane], e1);
    }
  }
  atomicMax(&maxb[0], mymax0);
  atomicMax(&maxb[1], mymax1);
  __syncthreads();
  int h0 = maxb[0], h1 = maxb[1];
  if (h0 >= w0 && h0 >= 0){
    int total = (h0 - w0 + 1)*DD;
    for (int q=t; q<total; q+=256){
      int o = q/DD, dim = q - o*DD;
      atomicAdd(&out[(bp*NB + w0 + o)*DD + dim], acc[o*DD + dim]);
    }
  }
  if (h1 >= w1 && h1 >= 0){
    int total = (h1 - w1 + 1)*DD;
    for (int q=t; q<total; q+=256){
      int o = q/DD, dim = q - o*DD;
      atomicAdd(&out[((bp+32)*NB + w1 + o)*DD + dim], acc[WIN*DD + o*DD + dim]);
    }
  }
}

extern "C" void kernel_launch(void* const* d_in, const int* in_sizes, int n_in,
                              void* d_out, int out_size, void* d_ws, size_t ws_size,
                              hipStream_t stream){
  const float* X = (const float*)d_in[0];
  const float* W = (const float*)d_in[1];
  float* out  = (float*)d_out;
  float* lsum = (float*)d_ws;                                        // 100000 f
  float* g    = (float*)((char*)d_ws + 400000);                      // 100000 f
  int8_t* bins = (int8_t*)((char*)d_ws + 800000);                    // 131072 B
  (void)in_sizes; (void)n_in; (void)ws_size;
  hipMemsetAsync(d_out, 0, (size_t)out_size*sizeof(float), stream);
  k_prep <<<NTOK/8, 256, 0, stream>>>((const float4*)W, lsum, g);
  k_bins <<<BB,     256, 0, stream>>>(X, lsum, g, bins, out);
  k_accum<<<2048,   256, 0, stream>>>(X, W, bins, out);
}

// Round 4
// 258.078 us; speedup vs baseline: 1.2718x; 1.0122x over previous
//
#include <hip/hip_runtime.h>
#include <stdint.h>
#include <math.h>

#define BB 64
#define SS 2048
#define DD 128
#define NB 48
#define NTOK 100000
#define HALF 8388608u   // (BB*SS*DD)/2 = 2^23
#define KL_OFF (BB*NB*DD) // 393216
#define WIN 8

__device__ __forceinline__ uint32_t rotl32(uint32_t x, uint32_t r){ return (x<<r)|(x>>(32u-r)); }

// JAX threefry2x32 with key = (0, 42) — bit-exact, do not touch.
__device__ __forceinline__ uint2 threefry_0_42(uint32_t x0, uint32_t x1){
  const uint32_t ks0 = 0u, ks1 = 42u, ks2 = 0x1BD11BDAu ^ 0u ^ 42u; // 0x1BD11BF0
  x0 += ks0; x1 += ks1;
#define TF_ROUND(r) { x0 += x1; x1 = rotl32(x1, r); x1 ^= x0; }
  TF_ROUND(13u) TF_ROUND(15u) TF_ROUND(26u) TF_ROUND(6u)
  x0 += ks1; x1 += ks2 + 1u;
  TF_ROUND(17u) TF_ROUND(29u) TF_ROUND(16u) TF_ROUND(24u)
  x0 += ks2; x1 += ks0 + 2u;
  TF_ROUND(13u) TF_ROUND(15u) TF_ROUND(26u) TF_ROUND(6u)
  x0 += ks0; x1 += ks1 + 3u;
  TF_ROUND(17u) TF_ROUND(29u) TF_ROUND(16u) TF_ROUND(24u)
  x0 += ks1; x1 += ks2 + 4u;
  TF_ROUND(13u) TF_ROUND(15u) TF_ROUND(26u) TF_ROUND(6u)
  x0 += ks2; x1 += ks0 + 5u;
#undef TF_ROUND
  return make_uint2(x0, x1);
}

// Branchless fast erfinv (Giles coeffs, HW log/sqrt). Tolerance-checked path only.
__device__ __forceinline__ float fast_erfinv(float x){
  float w = -__logf(__fmaf_rn(x, -x, 1.0f));
  bool c = w < 5.0f;
  float t = c ? (w - 2.5f) : (__builtin_amdgcn_sqrtf(w) - 3.0f);
  float p =              c ? 2.81022636e-08f : -0.000200214257f;
  p = __fmaf_rn(p, t,    c ? 3.43273939e-07f : 0.000100950558f);
  p = __fmaf_rn(p, t,    c ? -3.5233877e-06f : 0.00134934322f);
  p = __fmaf_rn(p, t,    c ? -4.39150654e-06f : -0.00367342844f);
  p = __fmaf_rn(p, t,    c ? 0.00021858087f  : 0.00573950773f);
  p = __fmaf_rn(p, t,    c ? -0.00125372503f : -0.0076224613f);
  p = __fmaf_rn(p, t,    c ? -0.00417768164f : 0.00943887047f);
  p = __fmaf_rn(p, t,    c ? 0.246640727f    : 1.00167406f);
  p = __fmaf_rn(p, t,    c ? 1.50140941f     : 2.83297682f);
  return p * x;
}

__device__ __forceinline__ float jax_normal_from_bits(uint32_t bits){
  float f   = __uint_as_float((bits >> 9) | 0x3F800000u);
  float u01 = f - 1.0f;                          // [0,1), exact
  const float lo = __uint_as_float(0xBF7FFFFFu); // nextafter(-1,0)
  float u = fmaxf(lo, __fmaf_rn(u01, 2.0f, lo));
  return 1.41421356237f * fast_erfinv(u);
}

// K0: unchanged from round 3 (passed). lsum association BIT-EXACT — do not touch.
__global__ __launch_bounds__(256) void k_prep(const float4* __restrict__ W4,
                                              float* __restrict__ lsum,
                                              float* __restrict__ g){
  __shared__ float mu_s[8][128];
  __shared__ float lv_s[8][128];
  __shared__ float gpart[8][32];
  __shared__ float apart[8][8];
  int t = threadIdx.x;
  int blk = blockIdx.x;
  #pragma unroll
  for (int h=0; h<2; h++){
    int q = h*256 + t;          // 0..511 = 8 tokens x 64 float4
    int r = q >> 6, c = q & 63;
    float4 v = W4[(size_t)blk*512 + q];
    if (c < 32) ((float4*)mu_s[r])[c]      = v;
    else        ((float4*)lv_s[r])[c - 32] = v;
  }
  __syncthreads();
  {
    int tl = t>>5, i = t&31;
    float gp = 0.f;
    #pragma unroll
    for (int c=0;c<4;c++){
      int d = i + 32*c;
      float mu = mu_s[tl][d], lv = lv_s[tl][d];
      gp += (-1.0f - lv) + mu*mu + __expf(lv);
    }
    gpart[tl][i] = gp;
  }
  if (t < 64){
    int tl = t>>3, j = t&7;
    float a = lv_s[tl][j];
    #pragma unroll
    for (int k=1;k<16;k++) a = __fadd_rn(a, lv_s[tl][8*k+j]);
    apart[tl][j] = a;
  }
  __syncthreads();
  if (t < 8){
    const float* p = apart[t];
    float s01 = __fadd_rn(p[0],p[1]);
    float s23 = __fadd_rn(p[2],p[3]);
    float s45 = __fadd_rn(p[4],p[5]);
    float s67 = __fadd_rn(p[6],p[7]);
    lsum[blk*8 + t] = __fadd_rn(__fadd_rn(s01,s23), __fadd_rn(s45,s67));
    float gs = 0.f;
    #pragma unroll
    for (int i=0;i<32;i++) gs += gpart[t][i];
    g[blk*8 + t] = gs;
  }
}

// K1: Brent-Kung scan — recursion arithmetic BYTE-IDENTICAL to verified version
// (only thread strides changed: 1024 threads; reductions via wave shuffles —
// max is exact under any order; kl sum is tolerance-checked).
__global__ __launch_bounds__(1024) void k_bins(const float* __restrict__ X, const float* __restrict__ lsum,
                                               const float* __restrict__ g,
                                               int8_t* __restrict__ bins, float* __restrict__ out){
  __shared__ float buf[4096];   // level L at offset 4096 - (4096>>L), size 2048>>L
  __shared__ float redm[16];
  __shared__ float redk[16];
  int b = blockIdx.x, t = threadIdx.x;
  float twopi_f = (float)(2.0 * M_PI);
  float L = (float)log((double)twopi_f);
  float C1 = __fadd_rn(128.0f, __fmul_rn(128.0f, L));
  float klacc = 0.f;
  for (int s=t; s<SS; s+=1024){
    float T    = X[(b*SS+s)*2 + 0];
    int   tok  = (int)X[(b*SS+s)*2 + 1];
    float ls   = lsum[tok];
    klacc     += g[tok];
    float h    = __fmul_rn(0.5f, __fadd_rn(C1, ls));
    float mask = (T < 48.0f) ? 1.0f : 0.0f;
    buf[s] = __fmul_rn(h, mask);
  }
  __syncthreads();
  {
    int offL = 0, sz = SS;
    for (int lev=0; lev<11; lev++){
      int n = sz >> 1; int offN = offL + sz;
      for (int k=t; k<n; k+=1024)
        buf[offN + k] = __fadd_rn(buf[offL + 2*k], buf[offL + 2*k + 1]);
      __syncthreads();
      offL = offN; sz = n;
    }
  }
  for (int lev=10; lev>=0; lev--){
    int offC = 4096 - (4096 >> lev);
    int offN = 4096 - (4096 >> (lev+1));
    int half = (2048 >> lev) >> 1;
    for (int k=t; k<half; k+=1024){
      float odd  = buf[offN + k];
      float even = (k == 0) ? buf[offC] : __fadd_rn(buf[offN + k - 1], buf[offC + 2*k]);
      buf[offC + 2*k]     = even;
      buf[offC + 2*k + 1] = odd;
    }
    __syncthreads();
  }
  // exact max via wave shuffles (order-independent)
  float m = fmaxf(buf[t], buf[t + 1024]);
  #pragma unroll
  for (int o=32; o>0; o>>=1) m = fmaxf(m, __shfl_down(m, o));
  if ((t & 63) == 0) redm[t >> 6] = m;
  __syncthreads();
  float maxv = redm[0];
  #pragma unroll
  for (int i=1;i<16;i++) maxv = fmaxf(maxv, redm[i]);
  for (int s=t; s<SS; s+=1024){
    float norm = __fdiv_rn(buf[s], maxv);
    int bin = (int)floorf(__fmul_rn(norm, 48.0f));
    bool valid = (norm >= 0.0f) && (norm < 1.0f);
    bins[b*SS + s] = valid ? (int8_t)bin : (int8_t)(-1);
  }
  // kl (tolerance-checked)
  #pragma unroll
  for (int o=32; o>0; o>>=1) klacc += __shfl_down(klacc, o);
  if ((t & 63) == 0) redk[t >> 6] = klacc;
  __syncthreads();
  if (t == 0){
    float s = 0.f;
    #pragma unroll
    for (int i=0;i<16;i++) s += redk[i];
    atomicAdd(&out[KL_OFF], s * (0.5f/64.0f));
  }
}

// K2: toks/bins staged in LDS; W gather prefetched 1 iter ahead; register-run
// accumulation (bin is wave-uniform & nondecreasing) with rare LDS flushes.
__global__ __launch_bounds__(256, 8) void k_accum(const float* __restrict__ X, const float* __restrict__ W,
                                                  const int8_t* __restrict__ bins,
                                                  float* __restrict__ out){
  __shared__ float acc[2*WIN*DD];   // 8 KB
  __shared__ int   tok_s[2][32];
  __shared__ int   bin_s[2][32];
  int t = threadIdx.x;
  int bp = blockIdx.x >> 6;          // rows (bp, bp+32)
  int chunk = blockIdx.x & 63;       // 32 positions
  int sub = t >> 7, lane = t & 127;
  for (int i=t; i<2*WIN*DD; i+=256) acc[i] = 0.f;
  if (t < 128){
    int r = (t >> 5) & 1, i = t & 31;
    int row = bp + r*32;
    if (t < 64) tok_s[r][i] = (int)X[(row*SS + chunk*32 + i)*2 + 1];
    else        bin_s[r][i] = (int)bins[row*SS + chunk*32 + i];
  }
  __syncthreads();
  int base0 = bin_s[0][0], base1 = bin_s[1][0];
  int hi0 = -1, hi1 = -1;
  #pragma unroll
  for (int i=0;i<32;i++){ hi0 = max(hi0, bin_s[0][i]); hi1 = max(hi1, bin_s[1][i]); }
  // prefetch it=0
  int tk0 = tok_s[0][sub], tk1 = tok_s[1][sub];
  float mu0 = W[tk0*256 + lane], lv0 = W[tk0*256 + 128 + lane];
  float mu1 = W[tk1*256 + lane], lv1 = W[tk1*256 + 128 + lane];
  int cur0 = -1, cur1 = -1;
  float r0 = 0.f, r1 = 0.f;
  #pragma unroll 4
  for (int it=0; it<16; it++){
    float mu0n=0.f, lv0n=0.f, mu1n=0.f, lv1n=0.f;
    if (it < 15){
      int sln = (it+1)*2 + sub;
      int a0 = tok_s[0][sln], a1 = tok_s[1][sln];
      mu0n = W[a0*256 + lane]; lv0n = W[a0*256 + 128 + lane];
      mu1n = W[a1*256 + lane]; lv1n = W[a1*256 + 128 + lane];
    }
    int s = chunk*32 + it*2 + sub;
    uint32_t i32 = (uint32_t)(bp*SS + s) * 128u + (uint32_t)lane;   // < 2^23
    uint2 rr = threefry_0_42(i32, i32 + HALF);
    float e0 = __fmaf_rn(__expf(0.5f*lv0), jax_normal_from_bits(rr.x), mu0);
    float e1 = __fmaf_rn(__expf(0.5f*lv1), jax_normal_from_bits(rr.y), mu1);
    int b0 = bin_s[0][it*2+sub];   // wave-uniform
    int b1 = bin_s[1][it*2+sub];
    if (b0 != cur0){               // wave-uniform branch
      if (cur0 >= 0){
        int o = cur0 - base0;
        if (o < WIN) atomicAdd(&acc[o*DD + lane], r0);
        else atomicAdd(&out[(bp*NB + cur0)*DD + lane], r0);
      }
      cur0 = b0; r0 = 0.f;
    }
    if (b0 >= 0) r0 += e0;
    if (b1 != cur1){
      if (cur1 >= 0){
        int o = cur1 - base1;
        if (o < WIN) atomicAdd(&acc[WIN*DD + o*DD + lane], r1);
        else atomicAdd(&out[((bp+32)*NB + cur1)*DD + lane], r1);
      }
      cur1 = b1; r1 = 0.f;
    }
    if (b1 >= 0) r1 += e1;
    mu0=mu0n; lv0=lv0n; mu1=mu1n; lv1=lv1n;
  }
  if (cur0 >= 0){
    int o = cur0 - base0;
    if (o < WIN) atomicAdd(&acc[o*DD + lane], r0);
    else atomicAdd(&out[(bp*NB + cur0)*DD + lane], r0);
  }
  if (cur1 >= 0){
    int o = cur1 - base1;
    if (o < WIN) atomicAdd(&acc[WIN*DD + o*DD + lane], r1);
    else atomicAdd(&out[((bp+32)*NB + cur1)*DD + lane], r1);
  }
  __syncthreads();
  int top0 = min(hi0, base0 + WIN - 1);
  if (base0 >= 0 && top0 >= base0){
    int total = (top0 - base0 + 1)*DD;
    for (int q=t; q<total; q+=256){
      int o = q >> 7, dim = q & 127;
      atomicAdd(&out[(bp*NB + base0 + o)*DD + dim], acc[o*DD + dim]);
    }
  }
  int top1 = min(hi1, base1 + WIN - 1);
  if (base1 >= 0 && top1 >= base1){
    int total = (top1 - base1 + 1)*DD;
    for (int q=t; q<total; q+=256){
      int o = q >> 7, dim = q & 127;
      atomicAdd(&out[((bp+32)*NB + base1 + o)*DD + dim], acc[WIN*DD + o*DD + dim]);
    }
  }
}

extern "C" void kernel_launch(void* const* d_in, const int* in_sizes, int n_in,
                              void* d_out, int out_size, void* d_ws, size_t ws_size,
                              hipStream_t stream){
  const float* X = (const float*)d_in[0];
  const float* W = (const float*)d_in[1];
  float* out  = (float*)d_out;
  float* lsum = (float*)d_ws;                                        // 100000 f
  float* g    = (float*)((char*)d_ws + 400000);                      // 100000 f
  int8_t* bins = (int8_t*)((char*)d_ws + 800000);                    // 131072 B
  (void)in_sizes; (void)n_in; (void)ws_size;
  hipMemsetAsync(d_out, 0, (size_t)out_size*sizeof(float), stream);
  k_prep <<<NTOK/8, 256, 0, stream>>>((const float4*)W, lsum, g);
  k_bins <<<BB,    1024, 0, stream>>>(X, lsum, g, bins, out);
  k_accum<<<2048,   256, 0, stream>>>(X, W, bins, out);
}

// Round 5
// 207.783 us; speedup vs baseline: 1.5796x; 1.2421x over previous
//
#include <hip/hip_runtime.h>
#include <stdint.h>
#include <math.h>

#define BB 64
#define SS 2048
#define DD 128
#define NB 48
#define NTOK 100000
#define HALF 8388608u   // (BB*SS*DD)/2 = 2^23
#define KL_OFF (BB*NB*DD) // 393216
#define WIN 8

__device__ __forceinline__ uint32_t rotl32(uint32_t x, uint32_t r){ return (x<<r)|(x>>(32u-r)); }

// JAX threefry2x32 with key = (0, 42) — bit-exact, do not touch.
__device__ __forceinline__ uint2 threefry_0_42(uint32_t x0, uint32_t x1){
  const uint32_t ks0 = 0u, ks1 = 42u, ks2 = 0x1BD11BDAu ^ 0u ^ 42u; // 0x1BD11BF0
  x0 += ks0; x1 += ks1;
#define TF_ROUND(r) { x0 += x1; x1 = rotl32(x1, r); x1 ^= x0; }
  TF_ROUND(13u) TF_ROUND(15u) TF_ROUND(26u) TF_ROUND(6u)
  x0 += ks1; x1 += ks2 + 1u;
  TF_ROUND(17u) TF_ROUND(29u) TF_ROUND(16u) TF_ROUND(24u)
  x0 += ks2; x1 += ks0 + 2u;
  TF_ROUND(13u) TF_ROUND(15u) TF_ROUND(26u) TF_ROUND(6u)
  x0 += ks0; x1 += ks1 + 3u;
  TF_ROUND(17u) TF_ROUND(29u) TF_ROUND(16u) TF_ROUND(24u)
  x0 += ks1; x1 += ks2 + 4u;
  TF_ROUND(13u) TF_ROUND(15u) TF_ROUND(26u) TF_ROUND(6u)
  x0 += ks2; x1 += ks0 + 5u;
#undef TF_ROUND
  return make_uint2(x0, x1);
}

// Branchless fast erfinv (Giles coeffs, HW log/sqrt). Tolerance-checked path only.
__device__ __forceinline__ float fast_erfinv(float x){
  float w = -__logf(__fmaf_rn(x, -x, 1.0f));
  bool c = w < 5.0f;
  float t = c ? (w - 2.5f) : (__builtin_amdgcn_sqrtf(w) - 3.0f);
  float p =              c ? 2.81022636e-08f : -0.000200214257f;
  p = __fmaf_rn(p, t,    c ? 3.43273939e-07f : 0.000100950558f);
  p = __fmaf_rn(p, t,    c ? -3.5233877e-06f : 0.00134934322f);
  p = __fmaf_rn(p, t,    c ? -4.39150654e-06f : -0.00367342844f);
  p = __fmaf_rn(p, t,    c ? 0.00021858087f  : 0.00573950773f);
  p = __fmaf_rn(p, t,    c ? -0.00125372503f : -0.0076224613f);
  p = __fmaf_rn(p, t,    c ? -0.00417768164f : 0.00943887047f);
  p = __fmaf_rn(p, t,    c ? 0.246640727f    : 1.00167406f);
  p = __fmaf_rn(p, t,    c ? 1.50140941f     : 2.83297682f);
  return p * x;
}

__device__ __forceinline__ float jax_normal_from_bits(uint32_t bits){
  float f   = __uint_as_float((bits >> 9) | 0x3F800000u);
  float u01 = f - 1.0f;                          // [0,1), exact
  const float lo = __uint_as_float(0xBF7FFFFFu); // nextafter(-1,0)
  float u = fmaxf(lo, __fmaf_rn(u01, 2.0f, lo));
  return 1.41421356237f * fast_erfinv(u);
}

// K0: unchanged (passed). lsum association BIT-EXACT — do not touch.
__global__ __launch_bounds__(256) void k_prep(const float4* __restrict__ W4,
                                              float* __restrict__ lsum,
                                              float* __restrict__ g){
  __shared__ float mu_s[8][128];
  __shared__ float lv_s[8][128];
  __shared__ float gpart[8][32];
  __shared__ float apart[8][8];
  int t = threadIdx.x;
  int blk = blockIdx.x;
  #pragma unroll
  for (int h=0; h<2; h++){
    int q = h*256 + t;          // 0..511 = 8 tokens x 64 float4
    int r = q >> 6, c = q & 63;
    float4 v = W4[(size_t)blk*512 + q];
    if (c < 32) ((float4*)mu_s[r])[c]      = v;
    else        ((float4*)lv_s[r])[c - 32] = v;
  }
  __syncthreads();
  {
    int tl = t>>5, i = t&31;
    float gp = 0.f;
    #pragma unroll
    for (int c=0;c<4;c++){
      int d = i + 32*c;
      float mu = mu_s[tl][d], lv = lv_s[tl][d];
      gp += (-1.0f - lv) + mu*mu + __expf(lv);
    }
    gpart[tl][i] = gp;
  }
  if (t < 64){
    int tl = t>>3, j = t&7;
    float a = lv_s[tl][j];
    #pragma unroll
    for (int k=1;k<16;k++) a = __fadd_rn(a, lv_s[tl][8*k+j]);
    apart[tl][j] = a;
  }
  __syncthreads();
  if (t < 8){
    const float* p = apart[t];
    float s01 = __fadd_rn(p[0],p[1]);
    float s23 = __fadd_rn(p[2],p[3]);
    float s45 = __fadd_rn(p[4],p[5]);
    float s67 = __fadd_rn(p[6],p[7]);
    lsum[blk*8 + t] = __fadd_rn(__fadd_rn(s01,s23), __fadd_rn(s45,s67));
    float gs = 0.f;
    #pragma unroll
    for (int i=0;i<32;i++) gs += gpart[t][i];
    g[blk*8 + t] = gs;
  }
}

// K1: Brent-Kung scan — recursion arithmetic BYTE-IDENTICAL to verified version.
__global__ __launch_bounds__(1024) void k_bins(const float* __restrict__ X, const float* __restrict__ lsum,
                                               const float* __restrict__ g,
                                               int8_t* __restrict__ bins, float* __restrict__ out){
  __shared__ float buf[4096];   // level L at offset 4096 - (4096>>L), size 2048>>L
  __shared__ float redm[16];
  __shared__ float redk[16];
  int b = blockIdx.x, t = threadIdx.x;
  float twopi_f = (float)(2.0 * M_PI);
  float L = (float)log((double)twopi_f);
  float C1 = __fadd_rn(128.0f, __fmul_rn(128.0f, L));
  float klacc = 0.f;
  for (int s=t; s<SS; s+=1024){
    float T    = X[(b*SS+s)*2 + 0];
    int   tok  = (int)X[(b*SS+s)*2 + 1];
    float ls   = lsum[tok];
    klacc     += g[tok];
    float h    = __fmul_rn(0.5f, __fadd_rn(C1, ls));
    float mask = (T < 48.0f) ? 1.0f : 0.0f;
    buf[s] = __fmul_rn(h, mask);
  }
  __syncthreads();
  {
    int offL = 0, sz = SS;
    for (int lev=0; lev<11; lev++){
      int n = sz >> 1; int offN = offL + sz;
      for (int k=t; k<n; k+=1024)
        buf[offN + k] = __fadd_rn(buf[offL + 2*k], buf[offL + 2*k + 1]);
      __syncthreads();
      offL = offN; sz = n;
    }
  }
  for (int lev=10; lev>=0; lev--){
    int offC = 4096 - (4096 >> lev);
    int offN = 4096 - (4096 >> (lev+1));
    int half = (2048 >> lev) >> 1;
    for (int k=t; k<half; k+=1024){
      float odd  = buf[offN + k];
      float even = (k == 0) ? buf[offC] : __fadd_rn(buf[offN + k - 1], buf[offC + 2*k]);
      buf[offC + 2*k]     = even;
      buf[offC + 2*k + 1] = odd;
    }
    __syncthreads();
  }
  float m = fmaxf(buf[t], buf[t + 1024]);
  #pragma unroll
  for (int o=32; o>0; o>>=1) m = fmaxf(m, __shfl_down(m, o));
  if ((t & 63) == 0) redm[t >> 6] = m;
  __syncthreads();
  float maxv = redm[0];
  #pragma unroll
  for (int i=1;i<16;i++) maxv = fmaxf(maxv, redm[i]);
  for (int s=t; s<SS; s+=1024){
    float norm = __fdiv_rn(buf[s], maxv);
    int bin = (int)floorf(__fmul_rn(norm, 48.0f));
    bool valid = (norm >= 0.0f) && (norm < 1.0f);
    bins[b*SS + s] = valid ? (int8_t)bin : (int8_t)(-1);
  }
  #pragma unroll
  for (int o=32; o>0; o>>=1) klacc += __shfl_down(klacc, o);
  if ((t & 63) == 0) redk[t >> 6] = klacc;
  __syncthreads();
  if (t == 0){
    float s = 0.f;
    #pragma unroll
    for (int i=0;i<16;i++) s += redk[i];
    atomicAdd(&out[KL_OFF], s * (0.5f/64.0f));
  }
}

// K2: LDS-staged toks/bins; depth-1 W prefetch (NO unroll pragma — with the
// 64-VGPR cap from (256,8), unroll-4 spilled ~400B/thread to scratch and
// produced 206 MB of HBM writes in round 4); register-run accumulation.
__global__ __launch_bounds__(256, 8) void k_accum(const float* __restrict__ X, const float* __restrict__ W,
                                                  const int8_t* __restrict__ bins,
                                                  float* __restrict__ out){
  __shared__ float acc[2*WIN*DD];   // 8 KB
  __shared__ int   tok_s[2][32];
  __shared__ int   bin_s[2][32];
  __shared__ int   hi_s[2];
  int t = threadIdx.x;
  int bp = blockIdx.x >> 6;          // rows (bp, bp+32)
  int chunk = blockIdx.x & 63;       // 32 positions
  int sub = t >> 7, lane = t & 127;
  for (int i=t; i<2*WIN*DD; i+=256) acc[i] = 0.f;
  if (t < 128){
    int r = (t >> 5) & 1, i = t & 31;
    int row = bp + r*32;
    if (t < 64) tok_s[r][i] = (int)X[(row*SS + chunk*32 + i)*2 + 1];
    else        bin_s[r][i] = (int)bins[row*SS + chunk*32 + i];
  }
  __syncthreads();
  if (t < 2){
    int h = -1;
    for (int i=0;i<32;i++) h = max(h, bin_s[t][i]);
    hi_s[t] = h;
  }
  int base0 = bin_s[0][0], base1 = bin_s[1][0];
  // prefetch it=0
  int tk0 = tok_s[0][sub], tk1 = tok_s[1][sub];
  float mu0 = W[tk0*256 + lane], lv0 = W[tk0*256 + 128 + lane];
  float mu1 = W[tk1*256 + lane], lv1 = W[tk1*256 + 128 + lane];
  int cur0 = -1, cur1 = -1;
  float r0 = 0.f, r1 = 0.f;
  for (int it=0; it<16; it++){
    float mu0n=0.f, lv0n=0.f, mu1n=0.f, lv1n=0.f;
    if (it < 15){
      int sln = (it+1)*2 + sub;
      int a0 = tok_s[0][sln], a1 = tok_s[1][sln];
      mu0n = W[a0*256 + lane]; lv0n = W[a0*256 + 128 + lane];
      mu1n = W[a1*256 + lane]; lv1n = W[a1*256 + 128 + lane];
    }
    int sl = it*2 + sub;
    int s = chunk*32 + sl;
    uint32_t i32 = (uint32_t)(bp*SS + s) * 128u + (uint32_t)lane;   // < 2^23
    uint2 rr = threefry_0_42(i32, i32 + HALF);
    float e0 = __fmaf_rn(__expf(0.5f*lv0), jax_normal_from_bits(rr.x), mu0);
    float e1 = __fmaf_rn(__expf(0.5f*lv1), jax_normal_from_bits(rr.y), mu1);
    int b0 = bin_s[0][sl];   // wave-uniform
    int b1 = bin_s[1][sl];
    if (b0 != cur0){         // wave-uniform branch
      if (cur0 >= 0){
        int o = cur0 - base0;
        if (o < WIN) atomicAdd(&acc[o*DD + lane], r0);
        else atomicAdd(&out[(bp*NB + cur0)*DD + lane], r0);
      }
      cur0 = b0; r0 = 0.f;
    }
    if (b0 >= 0) r0 += e0;
    if (b1 != cur1){
      if (cur1 >= 0){
        int o = cur1 - base1;
        if (o < WIN) atomicAdd(&acc[WIN*DD + o*DD + lane], r1);
        else atomicAdd(&out[((bp+32)*NB + cur1)*DD + lane], r1);
      }
      cur1 = b1; r1 = 0.f;
    }
    if (b1 >= 0) r1 += e1;
    mu0=mu0n; lv0=lv0n; mu1=mu1n; lv1=lv1n;
  }
  if (cur0 >= 0){
    int o = cur0 - base0;
    if (o < WIN) atomicAdd(&acc[o*DD + lane], r0);
    else atomicAdd(&out[(bp*NB + cur0)*DD + lane], r0);
  }
  if (cur1 >= 0){
    int o = cur1 - base1;
    if (o < WIN) atomicAdd(&acc[WIN*DD + o*DD + lane], r1);
    else atomicAdd(&out[((bp+32)*NB + cur1)*DD + lane], r1);
  }
  __syncthreads();
  int hi0 = hi_s[0], hi1 = hi_s[1];
  int top0 = min(hi0, base0 + WIN - 1);
  if (base0 >= 0 && top0 >= base0){
    int total = (top0 - base0 + 1)*DD;
    for (int q=t; q<total; q+=256){
      int o = q >> 7, dim = q & 127;
      atomicAdd(&out[(bp*NB + base0 + o)*DD + dim], acc[o*DD + dim]);
    }
  }
  int top1 = min(hi1, base1 + WIN - 1);
  if (base1 >= 0 && top1 >= base1){
    int total = (top1 - base1 + 1)*DD;
    for (int q=t; q<total; q+=256){
      int o = q >> 7, dim = q & 127;
      atomicAdd(&out[((bp+32)*NB + base1 + o)*DD + dim], acc[WIN*DD + o*DD + dim]);
    }
  }
}

extern "C" void kernel_launch(void* const* d_in, const int* in_sizes, int n_in,
                              void* d_out, int out_size, void* d_ws, size_t ws_size,
                              hipStream_t stream){
  const float* X = (const float*)d_in[0];
  const float* W = (const float*)d_in[1];
  float* out  = (float*)d_out;
  float* lsum = (float*)d_ws;                                        // 100000 f
  float* g    = (float*)((char*)d_ws + 400000);                      // 100000 f
  int8_t* bins = (int8_t*)((char*)d_ws + 800000);                    // 131072 B
  (void)in_sizes; (void)n_in; (void)ws_size;
  hipMemsetAsync(d_out, 0, (size_t)out_size*sizeof(float), stream);
  k_prep <<<NTOK/8, 256, 0, stream>>>((const float4*)W, lsum, g);
  k_bins <<<BB,    1024, 0, stream>>>(X, lsum, g, bins, out);
  k_accum<<<2048,   256, 0, stream>>>(X, W, bins, out);
}